// Round 1
// baseline (6072.835 us; speedup 1.0000x reference)
//
#include <hip/hip_runtime.h>

#define IN_F 48
#define EDGE_F 32
#define HID_F 128
#define OUT_F 64

// Phase 1: e = relu(efeat@We + be); m = nfeat[src]*e; atomic scatter-add into accA[dst], deg[dst]
__global__ void k_edge1(const float* __restrict__ efeat, const float* __restrict__ nfeat,
                        const int* __restrict__ src, const int* __restrict__ dst,
                        const float* __restrict__ We, const float* __restrict__ be,
                        float* __restrict__ accA, float* __restrict__ deg, int E) {
    int e = blockIdx.x * blockDim.x + threadIdx.x;
    if (e >= E) return;
    int s = src[e], d = dst[e];

    float ef[EDGE_F];
    const float4* ef4 = (const float4*)(efeat + (size_t)e * EDGE_F);
#pragma unroll
    for (int k = 0; k < EDGE_F / 4; ++k) {
        float4 v = ef4[k];
        ef[4 * k + 0] = v.x; ef[4 * k + 1] = v.y; ef[4 * k + 2] = v.z; ef[4 * k + 3] = v.w;
    }

    float acc[IN_F];
#pragma unroll
    for (int j = 0; j < IN_F; ++j) acc[j] = be[j];   // uniform -> s_load
#pragma unroll
    for (int k = 0; k < EDGE_F; ++k) {
        float ek = ef[k];
#pragma unroll
        for (int j = 0; j < IN_F; ++j) acc[j] = fmaf(ek, We[k * IN_F + j], acc[j]);  // We uniform -> s_load
    }

    float nv[IN_F];
    const float4* n4 = (const float4*)(nfeat + (size_t)s * IN_F);
#pragma unroll
    for (int k = 0; k < IN_F / 4; ++k) {
        float4 v = n4[k];
        nv[4 * k + 0] = v.x; nv[4 * k + 1] = v.y; nv[4 * k + 2] = v.z; nv[4 * k + 3] = v.w;
    }

    float* arow = accA + (size_t)d * IN_F;
#pragma unroll
    for (int j = 0; j < IN_F; ++j) {
        float v = fmaxf(acc[j], 0.0f) * nv[j];
        atomicAdd(arow + j, v);
    }
    atomicAdd(deg + d, 1.0f);
}

__global__ void k_inv(const float* __restrict__ deg, float* __restrict__ inv, int N) {
    int i = blockIdx.x * blockDim.x + threadIdx.x;
    if (i < N) inv[i] = 1.0f / fmaxf(deg[i], 1.0f);
}

__global__ void k_norm48(float* __restrict__ buf, const float* __restrict__ inv, int total) {
    int t = blockIdx.x * blockDim.x + threadIdx.x;
    if (t >= total) return;
    int i = t / IN_F;
    buf[t] *= inv[i];
}

// Phase 3: scatter h[src] = [nfeat, hn0][src] into accB[dst] (96-wide)
__global__ void k_scatter96(const float* __restrict__ nfeat, const float* __restrict__ hn0,
                            const int* __restrict__ src, const int* __restrict__ dst,
                            float* __restrict__ accB, int total) {
    int t = blockIdx.x * 256 + threadIdx.x;
    if (t >= total) return;
    int e = t / 96;
    int j = t - e * 96;
    int s = src[e], d = dst[e];
    float v = (j < IN_F) ? nfeat[(size_t)s * IN_F + j] : hn0[(size_t)s * IN_F + (j - IN_F)];
    atomicAdd(accB + (size_t)d * 96 + j, v);
}

// Phase 4: h1 = relu([nfeat,hn0] @ W1s + (accB*inv) @ W1n + b1)  -- 192 -> 128, wave-per-row
__global__ void k_mm1(const float* __restrict__ nfeat, const float* __restrict__ hn0,
                      const float* __restrict__ accB, const float* __restrict__ inv,
                      const float* __restrict__ W1s, const float* __restrict__ W1n,
                      const float* __restrict__ b1, float* __restrict__ h1, int N) {
    __shared__ float xs[4][192];
    int wv = threadIdx.x >> 6, lane = threadIdx.x & 63;
    int row = blockIdx.x * 4 + wv;
    int r = row < N ? row : N - 1;
    float iv = inv[r];
    for (int k = lane; k < 192; k += 64) {
        float v;
        if (k < 48)      v = nfeat[(size_t)r * 48 + k];
        else if (k < 96) v = hn0[(size_t)r * 48 + (k - 48)];
        else             v = accB[(size_t)r * 96 + (k - 96)] * iv;
        xs[wv][k] = v;
    }
    __syncthreads();
    int c0 = lane, c1 = lane + 64;
    float a0 = b1[c0], a1 = b1[c1];
#pragma unroll 4
    for (int k = 0; k < 96; ++k) {
        float xk = xs[wv][k];
        a0 = fmaf(xk, W1s[k * 128 + c0], a0);
        a1 = fmaf(xk, W1s[k * 128 + c1], a1);
    }
#pragma unroll 4
    for (int k = 0; k < 96; ++k) {
        float xk = xs[wv][96 + k];
        a0 = fmaf(xk, W1n[k * 128 + c0], a0);
        a1 = fmaf(xk, W1n[k * 128 + c1], a1);
    }
    if (row < N) {
        h1[(size_t)row * 128 + c0] = fmaxf(a0, 0.0f);
        h1[(size_t)row * 128 + c1] = fmaxf(a1, 0.0f);
    }
}

// Phase 5: scatter h1[src] into acc2[dst] (128-wide)
__global__ void k_scatter128(const float* __restrict__ h1,
                             const int* __restrict__ src, const int* __restrict__ dst,
                             float* __restrict__ acc2, int total) {
    int t = blockIdx.x * 256 + threadIdx.x;
    if (t >= total) return;
    int e = t >> 7;
    int j = t & 127;
    int s = src[e], d = dst[e];
    atomicAdd(acc2 + (size_t)d * 128 + j, h1[(size_t)s * 128 + j]);
}

// Phase 6: out = [h1, acc2*inv] @ [W2s;W2n] + b2  -- 256 -> 64, wave-per-row
__global__ void k_mm2(const float* __restrict__ h1, const float* __restrict__ acc2,
                      const float* __restrict__ inv,
                      const float* __restrict__ W2s, const float* __restrict__ W2n,
                      const float* __restrict__ b2, float* __restrict__ out, int N) {
    __shared__ float xs[4][256];
    int wv = threadIdx.x >> 6, lane = threadIdx.x & 63;
    int row = blockIdx.x * 4 + wv;
    int r = row < N ? row : N - 1;
    float iv = inv[r];
    for (int k = lane; k < 256; k += 64) {
        float v = (k < 128) ? h1[(size_t)r * 128 + k] : acc2[(size_t)r * 128 + (k - 128)] * iv;
        xs[wv][k] = v;
    }
    __syncthreads();
    float a = b2[lane];
#pragma unroll 4
    for (int k = 0; k < 128; ++k) a = fmaf(xs[wv][k], W2s[k * 64 + lane], a);
#pragma unroll 4
    for (int k = 0; k < 128; ++k) a = fmaf(xs[wv][128 + k], W2n[k * 64 + lane], a);
    if (row < N) out[(size_t)row * 64 + lane] = a;
}

extern "C" void kernel_launch(void* const* d_in, const int* in_sizes, int n_in,
                              void* d_out, int out_size, void* d_ws, size_t ws_size,
                              hipStream_t stream) {
    const float* nfeat = (const float*)d_in[0];
    const float* efeat = (const float*)d_in[1];
    const int*   src   = (const int*)d_in[2];
    const int*   dst   = (const int*)d_in[3];
    const float* We    = (const float*)d_in[4];
    const float* be    = (const float*)d_in[5];
    const float* W1s   = (const float*)d_in[6];
    const float* W1n   = (const float*)d_in[7];
    const float* b1    = (const float*)d_in[8];
    const float* W2s   = (const float*)d_in[9];
    const float* W2n   = (const float*)d_in[10];
    const float* b2    = (const float*)d_in[11];
    float* out = (float*)d_out;

    int N = in_sizes[0] / IN_F;
    int E = in_sizes[2];

    // workspace layout (floats):
    // deg [0,N) | inv [N,2N) | hn0 [2N,50N) | accB [50N,146N) | h1 [146N,274N)
    // acc2 aliases [2N,130N) (hn0+accB dead after k_mm1)
    float* ws   = (float*)d_ws;
    float* deg  = ws;
    float* inv  = ws + (size_t)N;
    float* hn0  = ws + (size_t)2 * N;
    float* accB = hn0 + (size_t)48 * N;
    float* h1   = accB + (size_t)96 * N;
    float* acc2 = hn0;  // alias, 128N floats

    // zero deg + hn0-accumulator + accB (contiguous [0,146N))
    hipMemsetAsync(ws, 0, (size_t)146 * N * sizeof(float), stream);

    k_edge1<<<(E + 255) / 256, 256, 0, stream>>>(efeat, nfeat, src, dst, We, be, hn0, deg, E);
    k_inv<<<(N + 255) / 256, 256, 0, stream>>>(deg, inv, N);
    k_norm48<<<((N * 48) + 255) / 256, 256, 0, stream>>>(hn0, inv, N * 48);

    int tot96 = E * 96;   // 153.6M < 2^31
    k_scatter96<<<(tot96 + 255) / 256, 256, 0, stream>>>(nfeat, hn0, src, dst, accB, tot96);

    k_mm1<<<(N + 3) / 4, 256, 0, stream>>>(nfeat, hn0, accB, inv, W1s, W1n, b1, h1, N);

    hipMemsetAsync(acc2, 0, (size_t)128 * N * sizeof(float), stream);

    int tot128 = E * 128; // 204.8M < 2^31
    k_scatter128<<<(tot128 + 255) / 256, 256, 0, stream>>>(h1, src, dst, acc2, tot128);

    k_mm2<<<(N + 3) / 4, 256, 0, stream>>>(h1, acc2, inv, W2s, W2n, b2, out, N);
}

// Round 2
// 2319.202 us; speedup vs baseline: 2.6185x; 2.6185x over previous
//
#include <hip/hip_runtime.h>

#define IN_F 48
#define EDGE_F 32
#define HID_F 128
#define OUT_F 64

// ---------------- counting-sort-by-dst preprocessing ----------------

__global__ void k_hist(const int* __restrict__ dst, int* __restrict__ cnt, int E) {
    int e = blockIdx.x * 256 + threadIdx.x;
    if (e < E) atomicAdd(&cnt[dst[e]], 1);
}

// inclusive scan of 1024-chunk -> offsets[1+g]; chunk totals -> blksum
__global__ void k_scan1(const int* __restrict__ cnt, int* __restrict__ offsets,
                        int* __restrict__ blksum, int N) {
    __shared__ int sh[1024];
    int tid = threadIdx.x;
    int g = blockIdx.x * 1024 + tid;
    sh[tid] = (g < N) ? cnt[g] : 0;
    __syncthreads();
#pragma unroll
    for (int off = 1; off < 1024; off <<= 1) {
        int t = (tid >= off) ? sh[tid - off] : 0;
        __syncthreads();
        sh[tid] += t;
        __syncthreads();
    }
    if (g < N) offsets[1 + g] = sh[tid];
    if (tid == 1023) blksum[blockIdx.x] = sh[tid];
}

// exclusive scan of block sums (nb <= 256), in place
__global__ void k_scan2(int* __restrict__ blksum, int nb) {
    __shared__ int sh[256];
    int tid = threadIdx.x;
    int orig = (tid < nb) ? blksum[tid] : 0;
    sh[tid] = orig;
    __syncthreads();
#pragma unroll
    for (int off = 1; off < 256; off <<= 1) {
        int t = (tid >= off) ? sh[tid - off] : 0;
        __syncthreads();
        sh[tid] += t;
        __syncthreads();
    }
    if (tid < nb) blksum[tid] = sh[tid] - orig;  // exclusive
}

__global__ void k_scan3(int* __restrict__ offsets, const int* __restrict__ blksum, int N) {
    int tid = threadIdx.x;
    int g = blockIdx.x * 1024 + tid;
    if (g < N) offsets[1 + g] += blksum[blockIdx.x];
    if (g == 0) offsets[0] = 0;
}

__global__ void k_inv(const int* __restrict__ offsets, float* __restrict__ inv, int N) {
    int i = blockIdx.x * 256 + threadIdx.x;
    if (i < N) {
        int deg = offsets[i + 1] - offsets[i];
        inv[i] = 1.0f / (float)max(deg, 1);
    }
}

__global__ void k_fill(const int* __restrict__ dst, const int* __restrict__ offsets,
                       int* __restrict__ cursor, int* __restrict__ eid, int E) {
    int e = blockIdx.x * 256 + threadIdx.x;
    if (e >= E) return;
    int d = dst[e];
    int p = atomicAdd(&cursor[d], 1);
    eid[offsets[d] + p] = e;
}

// ---------------- layer 1: fused edge-encoder + segment mean ----------------
// wave-per-node; thread j<48 owns output feature j (holds We column j in regs)
__global__ __launch_bounds__(256) void k_gather_edge(
    const float* __restrict__ efeat, const float* __restrict__ nfeat,
    const int* __restrict__ src, const int* __restrict__ eid,
    const int* __restrict__ offsets, const float* __restrict__ inv,
    const float* __restrict__ We, const float* __restrict__ be,
    float* __restrict__ hn0, int N)
{
    int node = blockIdx.x * 4 + (threadIdx.x >> 6);
    int j = threadIdx.x & 63;
    if (node >= N) return;
    int jj = (j < IN_F) ? j : 0;
    float Wcol[EDGE_F];
#pragma unroll
    for (int k = 0; k < EDGE_F; ++k) Wcol[k] = We[k * IN_F + jj];
    float bj = be[jj];
    int s0 = offsets[node], s1 = offsets[node + 1];
    float sum = 0.0f;
    for (int i = s0; i < s1; ++i) {
        int e = eid[i];
        int s = src[e];
        const float4* ef4 = (const float4*)(efeat + (size_t)e * EDGE_F);
        float acc = bj;
#pragma unroll
        for (int k4 = 0; k4 < EDGE_F / 4; ++k4) {
            float4 v = ef4[k4];
            acc = fmaf(v.x, Wcol[4 * k4 + 0], acc);
            acc = fmaf(v.y, Wcol[4 * k4 + 1], acc);
            acc = fmaf(v.z, Wcol[4 * k4 + 2], acc);
            acc = fmaf(v.w, Wcol[4 * k4 + 3], acc);
        }
        sum += fmaxf(acc, 0.0f) * nfeat[(size_t)s * IN_F + jj];
    }
    if (j < IN_F) hn0[(size_t)node * IN_F + j] = sum * inv[node];
}

// ---------------- layer 2 neighbor mean: h = [nfeat, hn0], 96-wide ----------------
// 128 threads per node (2 nodes per 256-block); thread j<96 owns feature j
__global__ __launch_bounds__(256) void k_gather96(
    const float* __restrict__ nfeat, const float* __restrict__ hn0,
    const int* __restrict__ src, const int* __restrict__ eid,
    const int* __restrict__ offsets, const float* __restrict__ inv,
    float* __restrict__ hn1m, int N)
{
    int node = blockIdx.x * 2 + (threadIdx.x >> 7);
    int j = threadIdx.x & 127;
    if (node >= N) return;
    int s0 = offsets[node], s1 = offsets[node + 1];
    int j2 = j - IN_F;
    float sum = 0.0f;
    for (int i = s0; i < s1; ++i) {
        int s = src[eid[i]];
        float v = (j < IN_F) ? nfeat[(size_t)s * IN_F + j]
                : (j < 96)   ? hn0[(size_t)s * IN_F + j2] : 0.0f;
        sum += v;
    }
    if (j < 96) hn1m[(size_t)node * 96 + j] = sum * inv[node];
}

// ---------------- layer 3 neighbor mean: h1, 128-wide ----------------
__global__ __launch_bounds__(256) void k_gather128(
    const float* __restrict__ h1,
    const int* __restrict__ src, const int* __restrict__ eid,
    const int* __restrict__ offsets, const float* __restrict__ inv,
    float* __restrict__ hn2, int N)
{
    int node = blockIdx.x * 2 + (threadIdx.x >> 7);
    int j = threadIdx.x & 127;
    if (node >= N) return;
    int s0 = offsets[node], s1 = offsets[node + 1];
    float sum = 0.0f;
    for (int i = s0; i < s1; ++i) {
        int s = src[eid[i]];
        sum += h1[(size_t)s * 128 + j];
    }
    hn2[(size_t)node * 128 + j] = sum * inv[node];
}

// ---------------- node matmuls ----------------
// h1 = relu([nfeat,hn0] @ W1s + hn1m @ W1n + b1)   (192 -> 128), wave-per-row
__global__ void k_mm1(const float* __restrict__ nfeat, const float* __restrict__ hn0,
                      const float* __restrict__ hn1m,
                      const float* __restrict__ W1s, const float* __restrict__ W1n,
                      const float* __restrict__ b1, float* __restrict__ h1, int N) {
    __shared__ float xs[4][192];
    int wv = threadIdx.x >> 6, lane = threadIdx.x & 63;
    int row = blockIdx.x * 4 + wv;
    int r = row < N ? row : N - 1;
    for (int k = lane; k < 192; k += 64) {
        float v;
        if (k < 48)      v = nfeat[(size_t)r * 48 + k];
        else if (k < 96) v = hn0[(size_t)r * 48 + (k - 48)];
        else             v = hn1m[(size_t)r * 96 + (k - 96)];
        xs[wv][k] = v;
    }
    __syncthreads();
    int c0 = lane, c1 = lane + 64;
    float a0 = b1[c0], a1 = b1[c1];
#pragma unroll 4
    for (int k = 0; k < 96; ++k) {
        float xk = xs[wv][k];
        a0 = fmaf(xk, W1s[k * 128 + c0], a0);
        a1 = fmaf(xk, W1s[k * 128 + c1], a1);
    }
#pragma unroll 4
    for (int k = 0; k < 96; ++k) {
        float xk = xs[wv][96 + k];
        a0 = fmaf(xk, W1n[k * 128 + c0], a0);
        a1 = fmaf(xk, W1n[k * 128 + c1], a1);
    }
    if (row < N) {
        h1[(size_t)row * 128 + c0] = fmaxf(a0, 0.0f);
        h1[(size_t)row * 128 + c1] = fmaxf(a1, 0.0f);
    }
}

// out = h1 @ W2s + hn2 @ W2n + b2   (256 -> 64), wave-per-row
__global__ void k_mm2(const float* __restrict__ h1, const float* __restrict__ hn2,
                      const float* __restrict__ W2s, const float* __restrict__ W2n,
                      const float* __restrict__ b2, float* __restrict__ out, int N) {
    __shared__ float xs[4][256];
    int wv = threadIdx.x >> 6, lane = threadIdx.x & 63;
    int row = blockIdx.x * 4 + wv;
    int r = row < N ? row : N - 1;
    for (int k = lane; k < 256; k += 64) {
        float v = (k < 128) ? h1[(size_t)r * 128 + k] : hn2[(size_t)r * 128 + (k - 128)];
        xs[wv][k] = v;
    }
    __syncthreads();
    float a = b2[lane];
#pragma unroll 4
    for (int k = 0; k < 128; ++k) a = fmaf(xs[wv][k], W2s[k * 64 + lane], a);
#pragma unroll 4
    for (int k = 0; k < 128; ++k) a = fmaf(xs[wv][128 + k], W2n[k * 64 + lane], a);
    if (row < N) out[(size_t)row * 64 + lane] = a;
}

extern "C" void kernel_launch(void* const* d_in, const int* in_sizes, int n_in,
                              void* d_out, int out_size, void* d_ws, size_t ws_size,
                              hipStream_t stream) {
    const float* nfeat = (const float*)d_in[0];
    const float* efeat = (const float*)d_in[1];
    const int*   src   = (const int*)d_in[2];
    const int*   dst   = (const int*)d_in[3];
    const float* We    = (const float*)d_in[4];
    const float* be    = (const float*)d_in[5];
    const float* W1s   = (const float*)d_in[6];
    const float* W1n   = (const float*)d_in[7];
    const float* b1    = (const float*)d_in[8];
    const float* W2s   = (const float*)d_in[9];
    const float* W2n   = (const float*)d_in[10];
    const float* b2    = (const float*)d_in[11];
    float* out = (float*)d_out;

    int N = in_sizes[0] / IN_F;
    int E = in_sizes[2];

    // workspace layout (4B units):
    // cursor[N] | offsets[N+64] | blksum[256] | inv[N] | eid[E] |
    // hn0[48N] | hn1m[96N] | h1[128N]
    // hn2[128N] aliases (hn0,hn1m) region (144N) -- both dead after k_mm1.
    int*   cursor  = (int*)d_ws;
    int*   offsets = cursor + N;
    int*   blksum  = offsets + N + 64;
    float* inv     = (float*)(blksum + 256);
    int*   eid     = (int*)(inv + N);
    float* hn0     = (float*)(eid + E);
    float* hn1m    = hn0 + (size_t)48 * N;
    float* h1      = hn1m + (size_t)96 * N;
    float* hn2     = hn0;  // alias: 128N <= 144N

    int nb = (N + 1023) / 1024;  // 98 for N=100000, must be <= 256

    hipMemsetAsync(cursor, 0, (size_t)N * sizeof(int), stream);
    k_hist<<<(E + 255) / 256, 256, 0, stream>>>(dst, cursor, E);
    k_scan1<<<nb, 1024, 0, stream>>>(cursor, offsets, blksum, N);
    k_scan2<<<1, 256, 0, stream>>>(blksum, nb);
    k_scan3<<<nb, 1024, 0, stream>>>(offsets, blksum, N);
    k_inv<<<(N + 255) / 256, 256, 0, stream>>>(offsets, inv, N);
    hipMemsetAsync(cursor, 0, (size_t)N * sizeof(int), stream);
    k_fill<<<(E + 255) / 256, 256, 0, stream>>>(dst, offsets, cursor, eid, E);

    k_gather_edge<<<(N + 3) / 4, 256, 0, stream>>>(efeat, nfeat, src, eid, offsets, inv,
                                                   We, be, hn0, N);
    k_gather96<<<(N + 1) / 2, 256, 0, stream>>>(nfeat, hn0, src, eid, offsets, inv, hn1m, N);
    k_mm1<<<(N + 3) / 4, 256, 0, stream>>>(nfeat, hn0, hn1m, W1s, W1n, b1, h1, N);
    k_gather128<<<(N + 1) / 2, 256, 0, stream>>>(h1, src, eid, offsets, inv, hn2, N);
    k_mm2<<<(N + 3) / 4, 256, 0, stream>>>(h1, hn2, W2s, W2n, b2, out, N);
}

// Round 3
// 1228.281 us; speedup vs baseline: 4.9442x; 1.8882x over previous
//
#include <hip/hip_runtime.h>

#define IN_F 48
#define EDGE_F 32
#define HID_F 128
#define OUT_F 64

// ---------------- counting-sort-by-dst preprocessing ----------------

__global__ void k_hist(const int* __restrict__ dst, int* __restrict__ cnt, int E) {
    int e = blockIdx.x * 256 + threadIdx.x;
    if (e < E) atomicAdd(&cnt[dst[e]], 1);
}

__global__ void k_scan1(const int* __restrict__ cnt, int* __restrict__ offsets,
                        int* __restrict__ blksum, int N) {
    __shared__ int sh[1024];
    int tid = threadIdx.x;
    int g = blockIdx.x * 1024 + tid;
    sh[tid] = (g < N) ? cnt[g] : 0;
    __syncthreads();
#pragma unroll
    for (int off = 1; off < 1024; off <<= 1) {
        int t = (tid >= off) ? sh[tid - off] : 0;
        __syncthreads();
        sh[tid] += t;
        __syncthreads();
    }
    if (g < N) offsets[1 + g] = sh[tid];
    if (tid == 1023) blksum[blockIdx.x] = sh[tid];
}

__global__ void k_scan2(int* __restrict__ blksum, int nb) {
    __shared__ int sh[256];
    int tid = threadIdx.x;
    int orig = (tid < nb) ? blksum[tid] : 0;
    sh[tid] = orig;
    __syncthreads();
#pragma unroll
    for (int off = 1; off < 256; off <<= 1) {
        int t = (tid >= off) ? sh[tid - off] : 0;
        __syncthreads();
        sh[tid] += t;
        __syncthreads();
    }
    if (tid < nb) blksum[tid] = sh[tid] - orig;  // exclusive
}

__global__ void k_scan3(int* __restrict__ offsets, const int* __restrict__ blksum, int N) {
    int g = blockIdx.x * 1024 + threadIdx.x;
    if (g < N) offsets[1 + g] += blksum[blockIdx.x];
    if (g == 0) offsets[0] = 0;
}

__global__ void k_inv(const int* __restrict__ offsets, float* __restrict__ inv, int N) {
    int i = blockIdx.x * 256 + threadIdx.x;
    if (i < N) {
        int deg = offsets[i + 1] - offsets[i];
        inv[i] = 1.0f / (float)max(deg, 1);
    }
}

// fill sorted edge ids AND sorted src ids (kills one indirection level in gathers)
__global__ void k_fill(const int* __restrict__ dst, const int* __restrict__ src,
                       const int* __restrict__ offsets,
                       int* __restrict__ cursor, int* __restrict__ eid,
                       int* __restrict__ srcs, int E) {
    int e = blockIdx.x * 256 + threadIdx.x;
    if (e >= E) return;
    int d = dst[e];
    int p = atomicAdd(&cursor[d], 1);
    int pos = offsets[d] + p;
    eid[pos] = e;
    srcs[pos] = src[e];
}

// ---------------- Path A: edge-parallel encoder -> msort, then streaming mean ----------------
__global__ void k_edge_msg(const float* __restrict__ efeat, const float* __restrict__ nfeat,
                           const int* __restrict__ eid, const int* __restrict__ srcs,
                           const float* __restrict__ We, const float* __restrict__ be,
                           float* __restrict__ msort, int E) {
    int i = blockIdx.x * 256 + threadIdx.x;
    if (i >= E) return;
    int e = eid[i], s = srcs[i];

    float ef[EDGE_F];
    const float4* ef4 = (const float4*)(efeat + (size_t)e * EDGE_F);
#pragma unroll
    for (int q = 0; q < EDGE_F / 4; ++q) {
        float4 v = ef4[q];
        ef[4 * q + 0] = v.x; ef[4 * q + 1] = v.y; ef[4 * q + 2] = v.z; ef[4 * q + 3] = v.w;
    }
    float acc[IN_F];
#pragma unroll
    for (int j = 0; j < IN_F; ++j) acc[j] = be[j];          // wave-uniform -> s_load
#pragma unroll
    for (int k = 0; k < EDGE_F; ++k) {
        float ek = ef[k];
#pragma unroll
        for (int j = 0; j < IN_F; ++j) acc[j] = fmaf(ek, We[k * IN_F + j], acc[j]);
    }
    const float4* n4 = (const float4*)(nfeat + (size_t)s * IN_F);
    float4* o4 = (float4*)(msort + (size_t)i * IN_F);
#pragma unroll
    for (int q = 0; q < IN_F / 4; ++q) {
        float4 nv = n4[q];
        float4 ov;
        ov.x = fmaxf(acc[4 * q + 0], 0.0f) * nv.x;
        ov.y = fmaxf(acc[4 * q + 1], 0.0f) * nv.y;
        ov.z = fmaxf(acc[4 * q + 2], 0.0f) * nv.z;
        ov.w = fmaxf(acc[4 * q + 3], 0.0f) * nv.w;
        o4[q] = ov;
    }
}

// streaming segment mean over contiguous msort rows (no indirection, pure stream)
__global__ __launch_bounds__(256) void k_gather48m(
    const float* __restrict__ msort, const int* __restrict__ offsets,
    const float* __restrict__ inv, float* __restrict__ hn0, int N) {
    int node = blockIdx.x * 4 + (threadIdx.x >> 6);
    int j = threadIdx.x & 63;
    if (node >= N) return;
    int jj = (j < IN_F) ? j : 0;
    int s0 = offsets[node], s1 = offsets[node + 1];
    float sum = 0.0f;
    int i = s0;
    for (; i + 4 <= s1; i += 4) {
        float a = msort[(size_t)(i + 0) * IN_F + jj];
        float b = msort[(size_t)(i + 1) * IN_F + jj];
        float c = msort[(size_t)(i + 2) * IN_F + jj];
        float d = msort[(size_t)(i + 3) * IN_F + jj];
        sum += (a + b) + (c + d);
    }
    for (; i < s1; ++i) sum += msort[(size_t)i * IN_F + jj];
    if (j < IN_F) hn0[(size_t)node * IN_F + j] = sum * inv[node];
}

// ---------------- Path B fallback: fused gather encoder (unroll 2, direct srcs) ----------------
__global__ __launch_bounds__(256) void k_gather_edge2(
    const float* __restrict__ efeat, const float* __restrict__ nfeat,
    const int* __restrict__ eid, const int* __restrict__ srcs,
    const int* __restrict__ offsets, const float* __restrict__ inv,
    const float* __restrict__ We, const float* __restrict__ be,
    float* __restrict__ hn0, int N) {
    int node = blockIdx.x * 4 + (threadIdx.x >> 6);
    int j = threadIdx.x & 63;
    if (node >= N) return;
    int jj = (j < IN_F) ? j : 0;
    float Wcol[EDGE_F];
#pragma unroll
    for (int k = 0; k < EDGE_F; ++k) Wcol[k] = We[k * IN_F + jj];
    float bj = be[jj];
    int s0 = offsets[node], s1 = offsets[node + 1];
    float sum = 0.0f;
    int i = s0;
    for (; i + 2 <= s1; i += 2) {
        int e0 = eid[i], e1 = eid[i + 1];
        int sA = srcs[i], sB = srcs[i + 1];
        const float4* p0 = (const float4*)(efeat + (size_t)e0 * EDGE_F);
        const float4* p1 = (const float4*)(efeat + (size_t)e1 * EDGE_F);
        float4 r0[8], r1[8];
#pragma unroll
        for (int q = 0; q < 8; ++q) r0[q] = p0[q];
#pragma unroll
        for (int q = 0; q < 8; ++q) r1[q] = p1[q];
        float nA = nfeat[(size_t)sA * IN_F + jj];
        float nB = nfeat[(size_t)sB * IN_F + jj];
        float a0 = bj, a1 = bj;
#pragma unroll
        for (int q = 0; q < 8; ++q) {
            a0 = fmaf(r0[q].x, Wcol[4 * q + 0], a0);
            a0 = fmaf(r0[q].y, Wcol[4 * q + 1], a0);
            a0 = fmaf(r0[q].z, Wcol[4 * q + 2], a0);
            a0 = fmaf(r0[q].w, Wcol[4 * q + 3], a0);
            a1 = fmaf(r1[q].x, Wcol[4 * q + 0], a1);
            a1 = fmaf(r1[q].y, Wcol[4 * q + 1], a1);
            a1 = fmaf(r1[q].z, Wcol[4 * q + 2], a1);
            a1 = fmaf(r1[q].w, Wcol[4 * q + 3], a1);
        }
        sum = fmaf(fmaxf(a0, 0.0f), nA, sum);
        sum = fmaf(fmaxf(a1, 0.0f), nB, sum);
    }
    for (; i < s1; ++i) {
        int e = eid[i], s = srcs[i];
        const float4* p0 = (const float4*)(efeat + (size_t)e * EDGE_F);
        float a0 = bj;
#pragma unroll
        for (int q = 0; q < 8; ++q) {
            float4 v = p0[q];
            a0 = fmaf(v.x, Wcol[4 * q + 0], a0);
            a0 = fmaf(v.y, Wcol[4 * q + 1], a0);
            a0 = fmaf(v.z, Wcol[4 * q + 2], a0);
            a0 = fmaf(v.w, Wcol[4 * q + 3], a0);
        }
        sum = fmaf(fmaxf(a0, 0.0f), nfeat[(size_t)s * IN_F + jj], sum);
    }
    if (j < IN_F) hn0[(size_t)node * IN_F + j] = sum * inv[node];
}

// ---------------- layer-2 neighbor mean: [nfeat, hn0], 96-wide, unroll 4 ----------------
__global__ __launch_bounds__(256) void k_gather96(
    const float* __restrict__ nfeat, const float* __restrict__ hn0,
    const int* __restrict__ srcs, const int* __restrict__ offsets,
    const float* __restrict__ inv, float* __restrict__ hn1m, int N) {
    int node = blockIdx.x * 2 + (threadIdx.x >> 7);
    int j = threadIdx.x & 127;
    if (node >= N) return;
    int jj = (j < 96) ? j : 95;
    const float* tab = (jj < IN_F) ? (nfeat + jj) : (hn0 + (jj - IN_F));
    int s0 = offsets[node], s1 = offsets[node + 1];
    float sum = 0.0f;
    int i = s0;
    for (; i + 4 <= s1; i += 4) {
        int sa = srcs[i], sb = srcs[i + 1], sc = srcs[i + 2], sd = srcs[i + 3];
        float va = tab[(size_t)sa * IN_F];
        float vb = tab[(size_t)sb * IN_F];
        float vc = tab[(size_t)sc * IN_F];
        float vd = tab[(size_t)sd * IN_F];
        sum += (va + vb) + (vc + vd);
    }
    for (; i < s1; ++i) sum += tab[(size_t)srcs[i] * IN_F];
    if (j < 96) hn1m[(size_t)node * 96 + j] = sum * inv[node];
}

// ---------------- layer-3 neighbor mean: h1, 128-wide, unroll 4 ----------------
__global__ __launch_bounds__(256) void k_gather128(
    const float* __restrict__ h1, const int* __restrict__ srcs,
    const int* __restrict__ offsets, const float* __restrict__ inv,
    float* __restrict__ hn2, int N) {
    int node = blockIdx.x * 2 + (threadIdx.x >> 7);
    int j = threadIdx.x & 127;
    if (node >= N) return;
    int s0 = offsets[node], s1 = offsets[node + 1];
    float sum = 0.0f;
    int i = s0;
    for (; i + 4 <= s1; i += 4) {
        int sa = srcs[i], sb = srcs[i + 1], sc = srcs[i + 2], sd = srcs[i + 3];
        float va = h1[(size_t)sa * 128 + j];
        float vb = h1[(size_t)sb * 128 + j];
        float vc = h1[(size_t)sc * 128 + j];
        float vd = h1[(size_t)sd * 128 + j];
        sum += (va + vb) + (vc + vd);
    }
    for (; i < s1; ++i) sum += h1[(size_t)srcs[i] * 128 + j];
    hn2[(size_t)node * 128 + j] = sum * inv[node];
}

// ---------------- node matmuls: 4 rows per wave (16 rows/block) ----------------
__global__ __launch_bounds__(256) void k_mm1(
    const float* __restrict__ nfeat, const float* __restrict__ hn0,
    const float* __restrict__ hn1m,
    const float* __restrict__ W1s, const float* __restrict__ W1n,
    const float* __restrict__ b1, float* __restrict__ h1, int N) {
    __shared__ float xs[16][192];
    int wv = threadIdx.x >> 6, lane = threadIdx.x & 63;
    int base = blockIdx.x * 16;
#pragma unroll
    for (int rr = 0; rr < 4; ++rr) {
        int row = base + wv * 4 + rr;
        int r = row < N ? row : N - 1;
        for (int k = lane; k < 192; k += 64) {
            float v;
            if (k < 48)      v = nfeat[(size_t)r * 48 + k];
            else if (k < 96) v = hn0[(size_t)r * 48 + (k - 48)];
            else             v = hn1m[(size_t)r * 96 + (k - 96)];
            xs[wv * 4 + rr][k] = v;
        }
    }
    __syncthreads();
    const float* x0 = xs[wv * 4 + 0];
    const float* x1 = xs[wv * 4 + 1];
    const float* x2 = xs[wv * 4 + 2];
    const float* x3 = xs[wv * 4 + 3];
    int c0 = lane, c1 = lane + 64;
    float a00 = b1[c0], a01 = b1[c1];
    float a10 = a00, a11 = a01, a20 = a00, a21 = a01, a30 = a00, a31 = a01;
#pragma unroll 4
    for (int k = 0; k < 96; ++k) {
        float w0 = W1s[k * 128 + c0], w1 = W1s[k * 128 + c1];
        a00 = fmaf(x0[k], w0, a00); a01 = fmaf(x0[k], w1, a01);
        a10 = fmaf(x1[k], w0, a10); a11 = fmaf(x1[k], w1, a11);
        a20 = fmaf(x2[k], w0, a20); a21 = fmaf(x2[k], w1, a21);
        a30 = fmaf(x3[k], w0, a30); a31 = fmaf(x3[k], w1, a31);
    }
#pragma unroll 4
    for (int k = 0; k < 96; ++k) {
        float w0 = W1n[k * 128 + c0], w1 = W1n[k * 128 + c1];
        a00 = fmaf(x0[96 + k], w0, a00); a01 = fmaf(x0[96 + k], w1, a01);
        a10 = fmaf(x1[96 + k], w0, a10); a11 = fmaf(x1[96 + k], w1, a11);
        a20 = fmaf(x2[96 + k], w0, a20); a21 = fmaf(x2[96 + k], w1, a21);
        a30 = fmaf(x3[96 + k], w0, a30); a31 = fmaf(x3[96 + k], w1, a31);
    }
    float accs[4][2] = {{a00, a01}, {a10, a11}, {a20, a21}, {a30, a31}};
#pragma unroll
    for (int rr = 0; rr < 4; ++rr) {
        int row = base + wv * 4 + rr;
        if (row < N) {
            h1[(size_t)row * 128 + c0] = fmaxf(accs[rr][0], 0.0f);
            h1[(size_t)row * 128 + c1] = fmaxf(accs[rr][1], 0.0f);
        }
    }
}

__global__ __launch_bounds__(256) void k_mm2(
    const float* __restrict__ h1, const float* __restrict__ hn2,
    const float* __restrict__ W2s, const float* __restrict__ W2n,
    const float* __restrict__ b2, float* __restrict__ out, int N) {
    __shared__ float xs[16][256];
    int wv = threadIdx.x >> 6, lane = threadIdx.x & 63;
    int base = blockIdx.x * 16;
#pragma unroll
    for (int rr = 0; rr < 4; ++rr) {
        int row = base + wv * 4 + rr;
        int r = row < N ? row : N - 1;
        for (int k = lane; k < 256; k += 64) {
            float v = (k < 128) ? h1[(size_t)r * 128 + k] : hn2[(size_t)r * 128 + (k - 128)];
            xs[wv * 4 + rr][k] = v;
        }
    }
    __syncthreads();
    const float* x0 = xs[wv * 4 + 0];
    const float* x1 = xs[wv * 4 + 1];
    const float* x2 = xs[wv * 4 + 2];
    const float* x3 = xs[wv * 4 + 3];
    float a0 = b2[lane], a1 = a0, a2 = a0, a3 = a0;
#pragma unroll 4
    for (int k = 0; k < 128; ++k) {
        float w = W2s[k * 64 + lane];
        a0 = fmaf(x0[k], w, a0); a1 = fmaf(x1[k], w, a1);
        a2 = fmaf(x2[k], w, a2); a3 = fmaf(x3[k], w, a3);
    }
#pragma unroll 4
    for (int k = 0; k < 128; ++k) {
        float w = W2n[k * 64 + lane];
        a0 = fmaf(x0[128 + k], w, a0); a1 = fmaf(x1[128 + k], w, a1);
        a2 = fmaf(x2[128 + k], w, a2); a3 = fmaf(x3[128 + k], w, a3);
    }
    float accs[4] = {a0, a1, a2, a3};
#pragma unroll
    for (int rr = 0; rr < 4; ++rr) {
        int row = base + wv * 4 + rr;
        if (row < N) out[(size_t)row * 64 + lane] = accs[rr];
    }
}

extern "C" void kernel_launch(void* const* d_in, const int* in_sizes, int n_in,
                              void* d_out, int out_size, void* d_ws, size_t ws_size,
                              hipStream_t stream) {
    const float* nfeat = (const float*)d_in[0];
    const float* efeat = (const float*)d_in[1];
    const int*   src   = (const int*)d_in[2];
    const int*   dst   = (const int*)d_in[3];
    const float* We    = (const float*)d_in[4];
    const float* be    = (const float*)d_in[5];
    const float* W1s   = (const float*)d_in[6];
    const float* W1n   = (const float*)d_in[7];
    const float* b1    = (const float*)d_in[8];
    const float* W2s   = (const float*)d_in[9];
    const float* W2n   = (const float*)d_in[10];
    const float* b2    = (const float*)d_in[11];
    float* out = (float*)d_out;

    int N = in_sizes[0] / IN_F;
    int E = in_sizes[2];

    // workspace layout (4B units), msort last so Path B needs no extra space:
    // cursor[N] | offsets[N+64] | blksum[256] | eid[E] | srcs[E] |
    // inv[N] | hn0[48N] | hn1m[96N] | h1[128N] | (msort[48E] if room)
    // hn2 aliases (hn0,hn1m) 144N >= 128N, both dead after k_mm1.
    int*   cursor  = (int*)d_ws;
    int*   offsets = cursor + N;
    int*   blksum  = offsets + N + 64;
    int*   eid     = blksum + 256;
    int*   srcs    = eid + E;
    float* inv     = (float*)(srcs + E);
    float* hn0     = inv + N;
    float* hn1m    = hn0 + (size_t)48 * N;
    float* h1      = hn1m + (size_t)96 * N;
    float* msort   = h1 + (size_t)128 * N;
    float* hn2     = hn0;  // alias

    size_t usedB   = (size_t)(msort - (float*)d_ws) * 4;            // bytes w/o msort
    size_t neededA = usedB + (size_t)48 * E * 4 + 64;               // + msort
    bool useMsort  = (ws_size >= neededA);

    int nb = (N + 1023) / 1024;  // 98 for N=100000 (<=256 required by k_scan2)

    hipMemsetAsync(cursor, 0, (size_t)N * sizeof(int), stream);
    k_hist<<<(E + 255) / 256, 256, 0, stream>>>(dst, cursor, E);
    k_scan1<<<nb, 1024, 0, stream>>>(cursor, offsets, blksum, N);
    k_scan2<<<1, 256, 0, stream>>>(blksum, nb);
    k_scan3<<<nb, 1024, 0, stream>>>(offsets, blksum, N);
    k_inv<<<(N + 255) / 256, 256, 0, stream>>>(offsets, inv, N);
    hipMemsetAsync(cursor, 0, (size_t)N * sizeof(int), stream);
    k_fill<<<(E + 255) / 256, 256, 0, stream>>>(dst, src, offsets, cursor, eid, srcs, E);

    if (useMsort) {
        k_edge_msg<<<(E + 255) / 256, 256, 0, stream>>>(efeat, nfeat, eid, srcs, We, be, msort, E);
        k_gather48m<<<(N + 3) / 4, 256, 0, stream>>>(msort, offsets, inv, hn0, N);
    } else {
        k_gather_edge2<<<(N + 3) / 4, 256, 0, stream>>>(efeat, nfeat, eid, srcs, offsets, inv,
                                                        We, be, hn0, N);
    }

    k_gather96<<<(N + 1) / 2, 256, 0, stream>>>(nfeat, hn0, srcs, offsets, inv, hn1m, N);
    k_mm1<<<(N + 15) / 16, 256, 0, stream>>>(nfeat, hn0, hn1m, W1s, W1n, b1, h1, N);
    k_gather128<<<(N + 1) / 2, 256, 0, stream>>>(h1, srcs, offsets, inv, hn2, N);
    k_mm2<<<(N + 15) / 16, 256, 0, stream>>>(h1, hn2, W2s, W2n, b2, out, N);
}